// Round 4
// baseline (497.077 us; speedup 1.0000x reference)
//
#include <hip/hip_runtime.h>

#define NN 100000
#define NE 3200000
#define NF 128
#define C1 32
#define C2 16
#define NG 64
#define BKT_SH 7
#define BKT_W  128
#define NBKT   782          // ceil(NN/128)
#define CH     8192         // edges per partition chunk
#define NW     391          // ceil(NE/CH)
#define RSTR   784          // runstart row stride (783 used)
#define MAPCAP 6400         // per-bucket flattened-edge capacity (mean 4092, sd 64)

// ---- workspace layout (4-byte element offsets) ----
// bcnt/pool/cntf adjacent -> ONE memset covers all zeroed state.
#define OFF_BCNT  0            // 1024 ints (782 used)
#define OFF_POOL  1024         // NG*C2 = 1024 floats
#define OFF_CNTF  2048         // NG floats (pad to 2304)
#define OFF_RUN   2304         // NW*RSTR = 306,544 ints -> 308,848
#define OFF_ROW   308848       // NN+1 ints -> 408,849 (pad to 408,864)
#define OFF_DIS   408864       // NN floats -> 508,864
#define OFF_EDG   508864       // NE uints (dead after fillfused); 16B aligned
// overlay on edgebuf after fillfused (NN*32 = NE exactly):
#define OFF_XS1H0 OFF_EDG                  // NN*8 uints: bf16x2 cols 0..15 (3.2MB, L2-fits)
#define OFF_XS1H1 (OFF_EDG + NN*8)         // NN*8 uints: bf16x2 cols 16..31 (3.2MB)
#define OFF_H1A   (OFF_EDG + NN*16)        // NN*16 floats: h cols 0..15 staging
#define OFF_XS2B  (OFF_EDG + NE)           // NN*8 uints bf16x2 (3.2MB, L2-fits)
#define OFF_COL   (OFF_XS2B + NN*8)        // NE ints CSR col indices

// ---- bf16x2 pack/unpack (RNE) ----
__device__ __forceinline__ unsigned pack_bf2(float a, float b) {
    unsigned ua = __float_as_uint(a);
    unsigned ub = __float_as_uint(b);
    ua = (ua + 0x7fffu + ((ua >> 16) & 1u)) >> 16;
    ub = (ub + 0x7fffu + ((ub >> 16) & 1u)) & 0xffff0000u;
    return ua | ub;   // lo = a, hi = b
}
__device__ __forceinline__ float2 unpack_bf2(unsigned u) {
    return make_float2(__uint_as_float(u << 16), __uint_as_float(u & 0xffff0000u));
}
__device__ __forceinline__ void acc4(float4& a, uint2 q) {
    float2 f0 = unpack_bf2(q.x), f1 = unpack_bf2(q.y);
    a.x += f0.x; a.y += f0.y; a.z += f1.x; a.w += f1.y;
}

// ---------------- k_part: per-chunk counting sort by bucket -----------------
__global__ __launch_bounds__(512) void k_part(
    const int* __restrict__ S, const int* __restrict__ D,
    unsigned* __restrict__ edgebuf, int* __restrict__ runstart,
    int* __restrict__ bcnt)
{
    __shared__ int lhist[1024];
    __shared__ int lstart[1024];
    __shared__ int lcur[NBKT];
    __shared__ int wsum[8];
    __shared__ unsigned lsort[CH];
    const int w = blockIdx.x;
    const int t = threadIdx.x;
    const int e0 = w * CH;
    const int n = min(CH, NE - e0);     // 8192 or 5120 (last); both %4 == 0
    const int n4 = n >> 2;
    const int4* __restrict__ S4 = (const int4*)(S + e0);
    const int4* __restrict__ D4 = (const int4*)(D + e0);

    for (int i = t; i < 1024; i += 512) lhist[i] = 0;
    __syncthreads();
    for (int i = t; i < n4; i += 512) {
        int4 d = D4[i];
        atomicAdd(&lhist[(unsigned)d.x >> BKT_SH], 1);
        atomicAdd(&lhist[(unsigned)d.y >> BKT_SH], 1);
        atomicAdd(&lhist[(unsigned)d.z >> BKT_SH], 1);
        atomicAdd(&lhist[(unsigned)d.w >> BKT_SH], 1);
    }
    __syncthreads();
    for (int i = t; i < NBKT; i += 512) atomicAdd(&bcnt[i], lhist[i]);

    int c0 = lhist[t * 2 + 0], c1 = lhist[t * 2 + 1];
    int ts = c0 + c1;
    const int lane = t & 63, wv = t >> 6;
    int sc = ts;
    #pragma unroll
    for (int off = 1; off < 64; off <<= 1) {
        int v = __shfl_up(sc, off, 64);
        if (lane >= off) sc += v;
    }
    if (lane == 63) wsum[wv] = sc;
    __syncthreads();
    int wo = 0;
    #pragma unroll
    for (int i = 0; i < 8; ++i) wo += (i < wv) ? wsum[i] : 0;
    int excl = sc - ts + wo;
    lstart[t * 2 + 0] = excl;
    lstart[t * 2 + 1] = excl + c0;
    __syncthreads();

    for (int i = t; i < 783; i += 512) runstart[w * RSTR + i] = lstart[i];
    for (int i = t; i < NBKT; i += 512) lcur[i] = lstart[i];
    __syncthreads();
    for (int i = t; i < n4; i += 512) {
        int4 s = S4[i];
        int4 d = D4[i];
        { int p = atomicAdd(&lcur[(unsigned)d.x >> BKT_SH], 1);
          lsort[p] = ((unsigned)s.x << BKT_SH) | ((unsigned)d.x & (BKT_W - 1)); }
        { int p = atomicAdd(&lcur[(unsigned)d.y >> BKT_SH], 1);
          lsort[p] = ((unsigned)s.y << BKT_SH) | ((unsigned)d.y & (BKT_W - 1)); }
        { int p = atomicAdd(&lcur[(unsigned)d.z >> BKT_SH], 1);
          lsort[p] = ((unsigned)s.z << BKT_SH) | ((unsigned)d.z & (BKT_W - 1)); }
        { int p = atomicAdd(&lcur[(unsigned)d.w >> BKT_SH], 1);
          lsort[p] = ((unsigned)s.w << BKT_SH) | ((unsigned)d.w & (BKT_W - 1)); }
    }
    __syncthreads();
    {
        uint4* __restrict__ eb4 = (uint4*)(edgebuf + e0);
        const uint4* __restrict__ ls4 = (const uint4*)lsort;
        for (int i = t; i < n4; i += 512) eb4[i] = ls4[i];
    }
}

// ---------------- fused per-bucket fill (bscan folded in) -------------------
__global__ __launch_bounds__(256) void k_fillfused(
    const unsigned* __restrict__ edgebuf, const int* __restrict__ runstart,
    const int* __restrict__ bcnt,
    int* __restrict__ rowstart, float* __restrict__ dis, int* __restrict__ colidx)
{
    __shared__ int rl[NW];
    __shared__ int pfx[NW];
    __shared__ int basea[NW];
    __shared__ unsigned short map[MAPCAP];
    __shared__ int lcnt[BKT_W];
    __shared__ int lcur[BKT_W];
    __shared__ int wsum[4];
    __shared__ int hs1;
    const int b = blockIdx.x;
    const int t = threadIdx.x;
    const int lane = t & 63, wv = t >> 6;

    // --- bs = sum(bcnt[0..b)) : strided + full-wave xor reduce
    int accp = 0;
    for (int i = t; i < b; i += 256) accp += bcnt[i];
    #pragma unroll
    for (int off = 1; off < 64; off <<= 1) accp += __shfl_xor(accp, off, 64);
    if (lane == 0) wsum[wv] = accp;

    for (int w = t; w < NW; w += 256) {
        int s0 = runstart[w * RSTR + b];
        int s1 = runstart[w * RSTR + b + 1];
        basea[w] = s0;
        rl[w] = s1 - s0;
    }
    if (t < BKT_W) lcnt[t] = 0;
    __syncthreads();
    const int bs = wsum[0] + wsum[1] + wsum[2] + wsum[3];

    // --- scan rl (391 entries, 2/thread, wave-shuffle)
    int w0 = t * 2;
    int c0 = (w0 < NW) ? rl[w0] : 0;
    int c1 = (w0 + 1 < NW) ? rl[w0 + 1] : 0;
    int ts = c0 + c1;
    int sc = ts;
    #pragma unroll
    for (int off = 1; off < 64; off <<= 1) {
        int v = __shfl_up(sc, off, 64);
        if (lane >= off) sc += v;
    }
    __syncthreads();                       // all bs-reads done before wsum reuse
    if (lane == 63) wsum[wv] = sc;
    __syncthreads();
    int wo = 0;
    #pragma unroll
    for (int i = 0; i < 4; ++i) wo += (i < wv) ? wsum[i] : 0;
    const int total = wsum[0] + wsum[1] + wsum[2] + wsum[3];
    int excl0 = sc - ts + wo;
    if (w0 < NW)     pfx[w0]     = excl0;
    if (w0 + 1 < NW) pfx[w0 + 1] = excl0 + c0;
    __syncthreads();

    for (int w = t; w < NW; w += 256) {
        int p = pfx[w], len = rl[w];
        basea[w] = w * CH + basea[w] - p;
        for (int i = 0; i < len; ++i) map[p + i] = (unsigned short)w;
    }
    __syncthreads();
    for (int j = t; j < total; j += 256) {
        unsigned p = edgebuf[basea[map[j]] + j];
        atomicAdd(&lcnt[p & (BKT_W - 1)], 1);
    }
    __syncthreads();

    // --- 128-wide scan of lcnt: 2-wave shuffle scan, 1 barrier
    int myc = 0, sc2 = 0;
    if (t < BKT_W) {
        myc = lcnt[t];
        sc2 = myc;
        #pragma unroll
        for (int off = 1; off < 64; off <<= 1) {
            int v = __shfl_up(sc2, off, 64);
            if (lane >= off) sc2 += v;
        }
        if (t == 63) hs1 = sc2;
    }
    __syncthreads();
    if (t < BKT_W) {
        int excl = sc2 - myc + ((t >= 64) ? hs1 : 0);
        int node = b * BKT_W + t;
        if (node < NN) {
            rowstart[node] = bs + excl;
            dis[node] = rsqrtf((float)myc + 1.0f);
        }
        lcur[t] = bs + excl;
    }
    if (b == 0 && t == 0) rowstart[NN] = NE;
    __syncthreads();
    for (int j = t; j < total; j += 256) {
        unsigned p = edgebuf[basea[map[j]] + j];
        int pos = atomicAdd(&lcur[p & (BKT_W - 1)], 1);
        colidx[pos] = (int)(p >> BKT_SH);
    }
}

// ---------------- GEMM1: split halves -> two 3.2MB tables -------------------
__global__ __launch_bounds__(256) void k_gemm1(
    const float* __restrict__ x, const float* __restrict__ W1,
    const float* __restrict__ dis,
    unsigned* __restrict__ xs1h0, unsigned* __restrict__ xs1h1)
{
    __shared__ float xls[128 * 33];
    __shared__ float wls[32 * 32];
    const int t = threadIdx.x;
    const int tc = t & 7;
    const int tr = t >> 3;
    const int base = blockIdx.x * 128;

    float a[4][4] = {};

    for (int k0 = 0; k0 < NF; k0 += 32) {
        {
            int i = t * 4;
            int kk = i >> 5, c = i & 31;
            *(float4*)&wls[kk * 32 + c] = *(const float4*)&W1[(k0 + kk) * C1 + c];
        }
        #pragma unroll
        for (int r = 0; r < 4; ++r) {
            int n = (t >> 3) + r * 32;
            int j = (t & 7) * 4;
            int node = base + n;
            float4 v = make_float4(0.f, 0.f, 0.f, 0.f);
            if (node < NN) v = *(const float4*)&x[(long long)node * NF + k0 + j];
            xls[n * 33 + j + 0] = v.x;
            xls[n * 33 + j + 1] = v.y;
            xls[n * 33 + j + 2] = v.z;
            xls[n * 33 + j + 3] = v.w;
        }
        __syncthreads();
        #pragma unroll 8
        for (int kk = 0; kk < 32; ++kk) {
            float4 w = *(const float4*)&wls[kk * 32 + tc * 4];
            #pragma unroll
            for (int i = 0; i < 4; ++i) {
                float xv = xls[(tr * 4 + i) * 33 + kk];
                a[i][0] = fmaf(xv, w.x, a[i][0]);
                a[i][1] = fmaf(xv, w.y, a[i][1]);
                a[i][2] = fmaf(xv, w.z, a[i][2]);
                a[i][3] = fmaf(xv, w.w, a[i][3]);
            }
        }
        __syncthreads();
    }
    #pragma unroll
    for (int i = 0; i < 4; ++i) {
        int node = base + tr * 4 + i;
        if (node < NN) {
            float dv = dis[node];
            uint2 o;
            o.x = pack_bf2(a[i][0] * dv, a[i][1] * dv);
            o.y = pack_bf2(a[i][2] * dv, a[i][3] * dv);
            unsigned* dst = (tc < 4) ? &xs1h0[node * 8 + tc * 2]
                                     : &xs1h1[node * 8 + (tc - 4) * 2];
            *(uint2*)dst = o;
        }
    }
}

// ---------------- gather pass over a 3.2MB half-table -----------------------
// One WAVE per node: lane = e*4 + l, e=0..15 edge slots, l=0..3 col groups.
// Balanced: wave runtime = ceil(deg/16), no max-of-8 divergence.
__device__ __forceinline__ float4 gather_half(
    const uint2* __restrict__ tb, const int* __restrict__ cp,
    int num, int v, int e, int l)
{
    float4 a = make_float4(0.f, 0.f, 0.f, 0.f);
    if (e == 0) acc4(a, tb[v * 4 + l]);                 // self loop
    int i = e;
    for (; i + 16 < num; i += 32) {                     // 2 gathers in flight
        int i0 = cp[i], i1 = cp[i + 16];
        uint2 q0 = tb[i0 * 4 + l];
        uint2 q1 = tb[i1 * 4 + l];
        acc4(a, q0); acc4(a, q1);
    }
    if (i < num) acc4(a, tb[cp[i] * 4 + l]);
    // reduce over e (lane bits 2..5)
    #pragma unroll
    for (int m = 4; m < 64; m <<= 1) {
        a.x += __shfl_xor(a.x, m, 64);
        a.y += __shfl_xor(a.y, m, 64);
        a.z += __shfl_xor(a.z, m, 64);
        a.w += __shfl_xor(a.w, m, 64);
    }
    return a;   // lanes 0..3 hold col groups 0..3
}

// pass A: cols 0..15 -> h1a (fp32)
__global__ __launch_bounds__(256) void k_g1a(
    const unsigned* __restrict__ xs1h0, const int* __restrict__ colidx,
    const int* __restrict__ rowstart, const float* __restrict__ dis,
    const float* __restrict__ b1, float* __restrict__ h1a)
{
    const int t = threadIdx.x;
    const int lane = t & 63;
    const int v = blockIdx.x * 4 + (t >> 6);   // NN = 25000*4 exactly
    const int l = lane & 3, e = lane >> 2;
    const int start = rowstart[v];
    const int num = rowstart[v + 1] - start;
    float4 a = gather_half((const uint2*)xs1h0, &colidx[start], num, v, e, l);
    if (e == 0) {
        float dv = dis[v];
        float4 o;
        o.x = fmaxf(fmaf(a.x, dv, b1[l * 4 + 0]), 0.f);
        o.y = fmaxf(fmaf(a.y, dv, b1[l * 4 + 1]), 0.f);
        o.z = fmaxf(fmaf(a.z, dv, b1[l * 4 + 2]), 0.f);
        o.w = fmaxf(fmaf(a.w, dv, b1[l * 4 + 3]), 0.f);
        *(float4*)&h1a[v * 16 + l * 4] = o;
    }
}

// pass B: cols 16..31, merge h1a, fused GEMM2 epilogue -> xs2b
__global__ __launch_bounds__(256) void k_g1b(
    const unsigned* __restrict__ xs1h1, const int* __restrict__ colidx,
    const int* __restrict__ rowstart, const float* __restrict__ dis,
    const float* __restrict__ b1, const float* __restrict__ h1a,
    const float* __restrict__ W2, unsigned* __restrict__ xs2b)
{
    __shared__ float w2s[C1 * C2];
    __shared__ float hrow[4][32];
    const int t = threadIdx.x;
    if (t < 128) *(float4*)&w2s[t * 4] = *(const float4*)&W2[t * 4];
    const int lane = t & 63, wv = t >> 6;
    const int v = blockIdx.x * 4 + wv;
    const int l = lane & 3, e = lane >> 2;
    const int start = rowstart[v];
    const int num = rowstart[v + 1] - start;
    float4 a = gather_half((const uint2*)xs1h1, &colidx[start], num, v, e, l);
    const float dv = dis[v];
    if (e == 0) {
        float4 hl = *(const float4*)&h1a[v * 16 + l * 4];
        *(float4*)&hrow[wv][l * 4] = hl;
        float4 o;
        o.x = fmaxf(fmaf(a.x, dv, b1[16 + l * 4 + 0]), 0.f);
        o.y = fmaxf(fmaf(a.y, dv, b1[16 + l * 4 + 1]), 0.f);
        o.z = fmaxf(fmaf(a.z, dv, b1[16 + l * 4 + 2]), 0.f);
        o.w = fmaxf(fmaf(a.w, dv, b1[16 + l * 4 + 3]), 0.f);
        *(float4*)&hrow[wv][16 + l * 4] = o;
    }
    __syncthreads();
    if (lane < 8) {                        // lane j: output cols 2j, 2j+1
        const float* hr = hrow[wv];
        float s0 = 0.f, s1 = 0.f;
        #pragma unroll
        for (int k = 0; k < 32; ++k) {
            float hv = hr[k];
            s0 = fmaf(hv, w2s[k * C2 + 2 * lane + 0], s0);
            s1 = fmaf(hv, w2s[k * C2 + 2 * lane + 1], s1);
        }
        xs2b[v * 8 + lane] = pack_bf2(s0 * dv, s1 * dv);
    }
}

// ---------------- gather layer2 + fused mean-pool (wave per node) -----------
__global__ __launch_bounds__(256) void k_gather2(
    const unsigned* __restrict__ xs2b, const int* __restrict__ colidx,
    const int* __restrict__ rowstart, const float* __restrict__ dis,
    const int* __restrict__ batch,
    float* __restrict__ pool, float* __restrict__ cntf)
{
    __shared__ float psum[NG * C2];
    __shared__ float cs[NG];
    const int t = threadIdx.x;
    for (int i = t; i < NG * C2; i += 256) psum[i] = 0.f;
    if (t < NG) cs[t] = 0.f;
    __syncthreads();

    const int lane = t & 63;
    const int v = blockIdx.x * 4 + (t >> 6);
    const int l = lane & 3, e = lane >> 2;
    const int start = rowstart[v];
    const int num = rowstart[v + 1] - start;
    float4 a = gather_half((const uint2*)xs2b, &colidx[start], num, v, e, l);
    if (e == 0) {
        float dv = dis[v];
        int g = batch[v];
        atomicAdd(&psum[g * C2 + l * 4 + 0], a.x * dv);
        atomicAdd(&psum[g * C2 + l * 4 + 1], a.y * dv);
        atomicAdd(&psum[g * C2 + l * 4 + 2], a.z * dv);
        atomicAdd(&psum[g * C2 + l * 4 + 3], a.w * dv);
        if (l == 0) atomicAdd(&cs[g], 1.0f);
    }
    __syncthreads();
    for (int i = t; i < NG * C2; i += 256)
        if (psum[i] != 0.f) atomicAdd(&pool[i], psum[i]);
    if (t < NG && cs[t] != 0.f) atomicAdd(&cntf[t], cs[t]);
}

// ---------------- final: out[g] = (pool/cnt + b2) @ lw + lb -----------------
__global__ void k_final(const float* __restrict__ pool, const float* __restrict__ cntf,
                        const float* __restrict__ b2,
                        const float* __restrict__ lw, const float* __restrict__ lb,
                        float* __restrict__ out)
{
    int g = threadIdx.x;
    if (g < NG) {
        float c = fmaxf(cntf[g], 1.0f);
        float inv = 1.0f / c;
        float s = lb[0];
        #pragma unroll
        for (int k = 0; k < C2; ++k) {
            s = fmaf(b2[k], lw[k], s);                    // bias fold
            s = fmaf(pool[g * C2 + k] * inv, lw[k], s);
        }
        out[g] = s;
    }
}

extern "C" void kernel_launch(void* const* d_in, const int* in_sizes, int n_in,
                              void* d_out, int out_size, void* d_ws, size_t ws_size,
                              hipStream_t stream) {
    const float* x     = (const float*)d_in[0];
    const int*   ei    = (const int*)d_in[1];
    const int*   batch = (const int*)d_in[2];
    const float* W1    = (const float*)d_in[3];
    const float* b1    = (const float*)d_in[4];
    const float* W2    = (const float*)d_in[5];
    const float* b2    = (const float*)d_in[6];
    const float* lw    = (const float*)d_in[7];
    const float* lb    = (const float*)d_in[8];
    float* out = (float*)d_out;

    float*    wsf = (float*)d_ws;
    int*      wsi = (int*)d_ws;
    unsigned* wsu = (unsigned*)d_ws;

    int*      bcnt     = wsi + OFF_BCNT;
    float*    pool     = wsf + OFF_POOL;
    float*    cntf     = wsf + OFF_CNTF;
    int*      runstart = wsi + OFF_RUN;
    int*      rowstart = wsi + OFF_ROW;
    float*    dis      = wsf + OFF_DIS;
    unsigned* edgebuf  = wsu + OFF_EDG;
    unsigned* xs1h0    = wsu + OFF_XS1H0;  // aliases edgebuf (dead after fillfused)
    unsigned* xs1h1    = wsu + OFF_XS1H1;
    float*    h1a      = wsf + OFF_H1A;
    unsigned* xs2b     = wsu + OFF_XS2B;
    int*      colidx   = wsi + OFF_COL;

    const int* S = ei;            // edge_index[0] (src)
    const int* D = ei + NE;       // edge_index[1] (dst)

    hipMemsetAsync(wsi + OFF_BCNT, 0, 2304 * sizeof(int), stream);  // bcnt+pool+cntf

    k_part       <<<NW, 512, 0, stream>>>(S, D, edgebuf, runstart, bcnt);
    k_fillfused  <<<NBKT, 256, 0, stream>>>(edgebuf, runstart, bcnt, rowstart, dis, colidx);
    k_gemm1      <<<(NN + 127) / 128, 256, 0, stream>>>(x, W1, dis, xs1h0, xs1h1);
    k_g1a        <<<NN / 4, 256, 0, stream>>>(xs1h0, colidx, rowstart, dis, b1, h1a);
    k_g1b        <<<NN / 4, 256, 0, stream>>>(xs1h1, colidx, rowstart, dis, b1, h1a, W2, xs2b);
    k_gather2    <<<NN / 4, 256, 0, stream>>>(xs2b, colidx, rowstart, dis, batch, pool, cntf);
    k_final      <<<1, 64, 0, stream>>>(pool, cntf, b2, lw, lb, out);
}

// Round 6
// 348.865 us; speedup vs baseline: 1.4248x; 1.4248x over previous
//
#include <hip/hip_runtime.h>

#define NN 100000
#define NE 3200000
#define NF 128
#define C1 32
#define C2 16
#define NG 64
#define BKT_SH 7
#define BKT_W  128
#define NBKT   782          // ceil(NN/128)
#define CH     8192         // edges per partition chunk
#define NW     391          // ceil(NE/CH)
#define RSTR   784          // runstart row stride (783 used)
#define MAPCAP 6400         // per-bucket flattened-edge capacity (mean 4092, sd 64)

// ---- workspace layout (4-byte element offsets) ----
// bcnt/pool/cntf/donecnt adjacent -> ONE memset covers all zeroed state.
#define OFF_BCNT  0            // 1024 ints (782 used)
#define OFF_POOL  1024         // NG*C2 = 1024 floats
#define OFF_CNTF  2048         // NG floats (pad to 2304)
#define OFF_DONE  2300         // 1 int (inside zeroed pad)
#define OFF_RUN   2304         // NW*RSTR = 306,544 ints -> 308,848
#define OFF_ROW   308848       // NN+1 ints -> 408,849 (pad to 408,864)
#define OFF_DIS   408864       // NN floats -> 508,864
#define OFF_EDG   508864       // NE uints (dead after fillfused); 16B aligned
// xs1 aliases edgebuf: ONLY legal because fillfused (last edgebuf reader) and
// gemm1 (xs1 writer) are SEPARATE kernels — do not fuse them (r5 fault).
#define OFF_XS1   OFF_EDG                  // NN*16 uints bf16x2 cols 0..31
#define OFF_XS2B  (OFF_EDG + NE)           // NN*8 uints bf16x2; 16B aligned
#define OFF_COL   (OFF_XS2B + NN*8)        // NE ints CSR col indices

// ---- bf16x2 pack/unpack (RNE) ----
__device__ __forceinline__ unsigned pack_bf2(float a, float b) {
    unsigned ua = __float_as_uint(a);
    unsigned ub = __float_as_uint(b);
    ua = (ua + 0x7fffu + ((ua >> 16) & 1u)) >> 16;
    ub = (ub + 0x7fffu + ((ub >> 16) & 1u)) & 0xffff0000u;
    return ua | ub;   // lo = a, hi = b
}
__device__ __forceinline__ float2 unpack_bf2(unsigned u) {
    return make_float2(__uint_as_float(u << 16), __uint_as_float(u & 0xffff0000u));
}
__device__ __forceinline__ void acc4(float4& a, uint2 q) {
    float2 f0 = unpack_bf2(q.x), f1 = unpack_bf2(q.y);
    a.x += f0.x; a.y += f0.y; a.z += f1.x; a.w += f1.y;
}

// ---------------- k_part: per-chunk counting sort by bucket -----------------
__global__ __launch_bounds__(512) void k_part(
    const int* __restrict__ S, const int* __restrict__ D,
    unsigned* __restrict__ edgebuf, int* __restrict__ runstart,
    int* __restrict__ bcnt)
{
    __shared__ int lhist[1024];
    __shared__ int lstart[1024];
    __shared__ int lcur[NBKT];
    __shared__ int wsum[8];
    __shared__ unsigned lsort[CH];
    const int w = blockIdx.x;
    const int t = threadIdx.x;
    const int e0 = w * CH;
    const int n = min(CH, NE - e0);     // 8192 or 5120 (last); both %4 == 0
    const int n4 = n >> 2;
    const int4* __restrict__ S4 = (const int4*)(S + e0);
    const int4* __restrict__ D4 = (const int4*)(D + e0);

    for (int i = t; i < 1024; i += 512) lhist[i] = 0;
    __syncthreads();
    for (int i = t; i < n4; i += 512) {
        int4 d = D4[i];
        atomicAdd(&lhist[(unsigned)d.x >> BKT_SH], 1);
        atomicAdd(&lhist[(unsigned)d.y >> BKT_SH], 1);
        atomicAdd(&lhist[(unsigned)d.z >> BKT_SH], 1);
        atomicAdd(&lhist[(unsigned)d.w >> BKT_SH], 1);
    }
    __syncthreads();
    for (int i = t; i < NBKT; i += 512) atomicAdd(&bcnt[i], lhist[i]);

    int c0 = lhist[t * 2 + 0], c1 = lhist[t * 2 + 1];
    int ts = c0 + c1;
    const int lane = t & 63, wv = t >> 6;
    int sc = ts;
    #pragma unroll
    for (int off = 1; off < 64; off <<= 1) {
        int v = __shfl_up(sc, off, 64);
        if (lane >= off) sc += v;
    }
    if (lane == 63) wsum[wv] = sc;
    __syncthreads();
    int wo = 0;
    #pragma unroll
    for (int i = 0; i < 8; ++i) wo += (i < wv) ? wsum[i] : 0;
    int excl = sc - ts + wo;
    lstart[t * 2 + 0] = excl;
    lstart[t * 2 + 1] = excl + c0;
    __syncthreads();

    for (int i = t; i < 783; i += 512) runstart[w * RSTR + i] = lstart[i];
    for (int i = t; i < NBKT; i += 512) lcur[i] = lstart[i];
    __syncthreads();
    for (int i = t; i < n4; i += 512) {
        int4 s = S4[i];
        int4 d = D4[i];
        { int p = atomicAdd(&lcur[(unsigned)d.x >> BKT_SH], 1);
          lsort[p] = ((unsigned)s.x << BKT_SH) | ((unsigned)d.x & (BKT_W - 1)); }
        { int p = atomicAdd(&lcur[(unsigned)d.y >> BKT_SH], 1);
          lsort[p] = ((unsigned)s.y << BKT_SH) | ((unsigned)d.y & (BKT_W - 1)); }
        { int p = atomicAdd(&lcur[(unsigned)d.z >> BKT_SH], 1);
          lsort[p] = ((unsigned)s.z << BKT_SH) | ((unsigned)d.z & (BKT_W - 1)); }
        { int p = atomicAdd(&lcur[(unsigned)d.w >> BKT_SH], 1);
          lsort[p] = ((unsigned)s.w << BKT_SH) | ((unsigned)d.w & (BKT_W - 1)); }
    }
    __syncthreads();
    {
        uint4* __restrict__ eb4 = (uint4*)(edgebuf + e0);
        const uint4* __restrict__ ls4 = (const uint4*)lsort;
        for (int i = t; i < n4; i += 512) eb4[i] = ls4[i];
    }
}

// ---------------- fused per-bucket fill (bscan folded, LDS edge staging) ----
__global__ __launch_bounds__(256) void k_fillfused(
    const unsigned* __restrict__ edgebuf, const int* __restrict__ runstart,
    const int* __restrict__ bcnt,
    int* __restrict__ rowstart, float* __restrict__ dis, int* __restrict__ colidx)
{
    __shared__ int rl[NW];
    __shared__ int pfx[NW];
    __shared__ int basea[NW];
    __shared__ unsigned short map[MAPCAP];
    __shared__ unsigned ebuf[MAPCAP];     // staged edges: global read ONCE
    __shared__ int lcnt[BKT_W];
    __shared__ int lcur[BKT_W];
    __shared__ int wsum[4];
    __shared__ int hs1;
    const int b = blockIdx.x;
    const int t = threadIdx.x;
    const int lane = t & 63, wv = t >> 6;

    // --- bs = sum(bcnt[0..b)) : strided + full-wave xor reduce
    int accp = 0;
    for (int i = t; i < b; i += 256) accp += bcnt[i];
    #pragma unroll
    for (int off = 1; off < 64; off <<= 1) accp += __shfl_xor(accp, off, 64);
    if (lane == 0) wsum[wv] = accp;

    for (int w = t; w < NW; w += 256) {
        int s0 = runstart[w * RSTR + b];
        int s1 = runstart[w * RSTR + b + 1];
        basea[w] = s0;
        rl[w] = s1 - s0;
    }
    if (t < BKT_W) lcnt[t] = 0;
    __syncthreads();
    const int bs = wsum[0] + wsum[1] + wsum[2] + wsum[3];

    // --- scan rl (391 entries, 2/thread, wave-shuffle)
    int w0 = t * 2;
    int c0 = (w0 < NW) ? rl[w0] : 0;
    int c1 = (w0 + 1 < NW) ? rl[w0 + 1] : 0;
    int ts = c0 + c1;
    int sc = ts;
    #pragma unroll
    for (int off = 1; off < 64; off <<= 1) {
        int v = __shfl_up(sc, off, 64);
        if (lane >= off) sc += v;
    }
    __syncthreads();                       // all bs-reads done before wsum reuse
    if (lane == 63) wsum[wv] = sc;
    __syncthreads();
    int wo = 0;
    #pragma unroll
    for (int i = 0; i < 4; ++i) wo += (i < wv) ? wsum[i] : 0;
    const int total = wsum[0] + wsum[1] + wsum[2] + wsum[3];
    int excl0 = sc - ts + wo;
    if (w0 < NW)     pfx[w0]     = excl0;
    if (w0 + 1 < NW) pfx[w0 + 1] = excl0 + c0;
    __syncthreads();

    for (int w = t; w < NW; w += 256) {
        int p = pfx[w], len = rl[w];
        basea[w] = w * CH + basea[w] - p;
        for (int i = 0; i < len; ++i) map[p + i] = (unsigned short)w;
    }
    __syncthreads();
    // count pass: read each edge ONCE from global, stage in LDS
    for (int j = t; j < total; j += 256) {
        unsigned p = edgebuf[basea[map[j]] + j];
        ebuf[j] = p;
        atomicAdd(&lcnt[p & (BKT_W - 1)], 1);
    }
    __syncthreads();

    // --- 128-wide scan of lcnt: 2-wave shuffle scan, 1 barrier
    int myc = 0, sc2 = 0;
    if (t < BKT_W) {
        myc = lcnt[t];
        sc2 = myc;
        #pragma unroll
        for (int off = 1; off < 64; off <<= 1) {
            int v = __shfl_up(sc2, off, 64);
            if (lane >= off) sc2 += v;
        }
        if (t == 63) hs1 = sc2;
    }
    __syncthreads();
    if (t < BKT_W) {
        int excl = sc2 - myc + ((t >= 64) ? hs1 : 0);
        int node = b * BKT_W + t;
        if (node < NN) {
            rowstart[node] = bs + excl;
            dis[node] = rsqrtf((float)myc + 1.0f);
        }
        lcur[t] = bs + excl;
    }
    if (b == 0 && t == 0) rowstart[NN] = NE;
    __syncthreads();
    // scatter pass from LDS-staged edges (no second global edgebuf read)
    for (int j = t; j < total; j += 256) {
        unsigned p = ebuf[j];
        int pos = atomicAdd(&lcur[p & (BKT_W - 1)], 1);
        colidx[pos] = (int)(p >> BKT_SH);
    }
}

// ---------------- GEMM1: xs1 = bf16x2{(x @ W1) * dis}, 64B/node row ---------
__global__ __launch_bounds__(256) void k_gemm1(
    const float* __restrict__ x, const float* __restrict__ W1,
    const float* __restrict__ dis,
    unsigned* __restrict__ xs1)
{
    __shared__ float xls[128 * 33];
    __shared__ float wls[32 * 32];
    const int t = threadIdx.x;
    const int tc = t & 7;
    const int tr = t >> 3;
    const int base = blockIdx.x * 128;

    float a[4][4] = {};

    for (int k0 = 0; k0 < NF; k0 += 32) {
        {
            int i = t * 4;
            int kk = i >> 5, c = i & 31;
            *(float4*)&wls[kk * 32 + c] = *(const float4*)&W1[(k0 + kk) * C1 + c];
        }
        #pragma unroll
        for (int r = 0; r < 4; ++r) {
            int n = (t >> 3) + r * 32;
            int j = (t & 7) * 4;
            int node = base + n;
            float4 v = make_float4(0.f, 0.f, 0.f, 0.f);
            if (node < NN) v = *(const float4*)&x[(long long)node * NF + k0 + j];
            xls[n * 33 + j + 0] = v.x;
            xls[n * 33 + j + 1] = v.y;
            xls[n * 33 + j + 2] = v.z;
            xls[n * 33 + j + 3] = v.w;
        }
        __syncthreads();
        #pragma unroll 8
        for (int kk = 0; kk < 32; ++kk) {
            float4 w = *(const float4*)&wls[kk * 32 + tc * 4];
            #pragma unroll
            for (int i = 0; i < 4; ++i) {
                float xv = xls[(tr * 4 + i) * 33 + kk];
                a[i][0] = fmaf(xv, w.x, a[i][0]);
                a[i][1] = fmaf(xv, w.y, a[i][1]);
                a[i][2] = fmaf(xv, w.z, a[i][2]);
                a[i][3] = fmaf(xv, w.w, a[i][3]);
            }
        }
        __syncthreads();
    }
    #pragma unroll
    for (int i = 0; i < 4; ++i) {
        int node = base + tr * 4 + i;
        if (node < NN) {
            float dv = dis[node];
            uint2 o;
            o.x = pack_bf2(a[i][0] * dv, a[i][1] * dv);
            o.y = pack_bf2(a[i][2] * dv, a[i][3] * dv);
            *(uint2*)&xs1[node * 16 + tc * 2] = o;
        }
    }
}

// ---------------- gather layer1 + fused GEMM2 epilogue (r3, unchanged) ------
__global__ __launch_bounds__(256) void k_gather1(
    const unsigned* __restrict__ xs1, const int* __restrict__ colidx,
    const int* __restrict__ rowstart, const float* __restrict__ dis,
    const float* __restrict__ b1, const float* __restrict__ W2,
    unsigned* __restrict__ xs2b)
{
    __shared__ float w2s[C1 * C2];
    __shared__ float hrow[32 * 33];
    const int t = threadIdx.x;
    if (t < 128) *(float4*)&w2s[t * 4] = *(const float4*)&W2[t * 4];
    const int l = t & 7;
    const int n = t >> 3;
    const int v = blockIdx.x * 32 + n;   // NN = 100000 = 3125*32 exactly

    const int start = rowstart[v];
    const int num = rowstart[v + 1] - start;
    const int* __restrict__ cp = &colidx[start];
    const uint2* __restrict__ tb = (const uint2*)xs1;   // row v = tb[v*8 + l]
    float4 a0 = make_float4(0.f, 0.f, 0.f, 0.f);
    float4 a1 = a0, a2 = a0, a3 = a0;
    acc4(a0, tb[v * 8 + l]);                            // self loop
    int i = 0;
    if (num >= 8) {
        int idx[8];
        #pragma unroll
        for (int j = 0; j < 8; ++j) idx[j] = cp[j];
        for (; i + 16 <= num; i += 8) {
            int nx[8];
            #pragma unroll
            for (int j = 0; j < 8; ++j) nx[j] = cp[i + 8 + j];
            uint2 q[8];
            #pragma unroll
            for (int j = 0; j < 8; ++j) q[j] = tb[idx[j] * 8 + l];
            acc4(a0, q[0]); acc4(a1, q[1]); acc4(a2, q[2]); acc4(a3, q[3]);
            acc4(a0, q[4]); acc4(a1, q[5]); acc4(a2, q[6]); acc4(a3, q[7]);
            #pragma unroll
            for (int j = 0; j < 8; ++j) idx[j] = nx[j];
        }
        {   // drain the pipelined 8
            uint2 q[8];
            #pragma unroll
            for (int j = 0; j < 8; ++j) q[j] = tb[idx[j] * 8 + l];
            acc4(a0, q[0]); acc4(a1, q[1]); acc4(a2, q[2]); acc4(a3, q[3]);
            acc4(a0, q[4]); acc4(a1, q[5]); acc4(a2, q[6]); acc4(a3, q[7]);
            i += 8;
        }
    }
    for (; i < num; ++i) acc4(a0, tb[cp[i] * 8 + l]);
    float ax = (a0.x + a1.x) + (a2.x + a3.x);
    float ay = (a0.y + a1.y) + (a2.y + a3.y);
    float az = (a0.z + a1.z) + (a2.z + a3.z);
    float aw = (a0.w + a1.w) + (a2.w + a3.w);
    const float dv = dis[v];

    hrow[n * 33 + l * 4 + 0] = fmaxf(fmaf(ax, dv, b1[l * 4 + 0]), 0.f);
    hrow[n * 33 + l * 4 + 1] = fmaxf(fmaf(ay, dv, b1[l * 4 + 1]), 0.f);
    hrow[n * 33 + l * 4 + 2] = fmaxf(fmaf(az, dv, b1[l * 4 + 2]), 0.f);
    hrow[n * 33 + l * 4 + 3] = fmaxf(fmaf(aw, dv, b1[l * 4 + 3]), 0.f);
    __syncthreads();

    // GEMM2 epilogue: lane l computes output cols 2l, 2l+1
    const float* hr = &hrow[n * 33];
    float s0 = 0.f, s1 = 0.f;
    #pragma unroll
    for (int k = 0; k < 32; ++k) {
        float hv = hr[k];
        s0 = fmaf(hv, w2s[k * C2 + 2 * l + 0], s0);
        s1 = fmaf(hv, w2s[k * C2 + 2 * l + 1], s1);
    }
    xs2b[v * 8 + l] = pack_bf2(s0 * dv, s1 * dv);
}

// ---------------- gather layer2 + mean-pool + fused final (last block) ------
__global__ __launch_bounds__(256) void k_gather2(
    const unsigned* __restrict__ xs2b, const int* __restrict__ colidx,
    const int* __restrict__ rowstart, const float* __restrict__ dis,
    const int* __restrict__ batch,
    float* __restrict__ pool, float* __restrict__ cntf, int* __restrict__ donecnt,
    const float* __restrict__ b2, const float* __restrict__ lw,
    const float* __restrict__ lb, float* __restrict__ out)
{
    __shared__ float psum[NG * C2];
    __shared__ float cs[NG];
    __shared__ int lastflag;
    const int t = threadIdx.x;
    for (int i = t; i < NG * C2; i += 256) psum[i] = 0.f;
    if (t < NG) cs[t] = 0.f;
    __syncthreads();

    const int l = t & 3;
    const int n = t >> 2;                 // 0..63
    const int v = blockIdx.x * 64 + n;
    const bool valid = v < NN;
    const int lane = t & 63;

    float4 r = make_float4(0.f, 0.f, 0.f, 0.f);
    int g = 0;
    if (valid) {
        const int start = rowstart[v];
        const int num = rowstart[v + 1] - start;
        const int* __restrict__ cp = &colidx[start];
        const uint2* __restrict__ tb = (const uint2*)xs2b;  // row v = tb[v*4 + l]
        float4 a0 = make_float4(0.f, 0.f, 0.f, 0.f);
        float4 a1 = a0, a2 = a0, a3 = a0;
        acc4(a0, tb[v * 4 + l]);                            // self loop
        int i = 0;
        if (num >= 8) {
            int idx[8];
            #pragma unroll
            for (int j = 0; j < 8; ++j) idx[j] = cp[j];
            for (; i + 16 <= num; i += 8) {
                int nx[8];
                #pragma unroll
                for (int j = 0; j < 8; ++j) nx[j] = cp[i + 8 + j];
                uint2 q[8];
                #pragma unroll
                for (int j = 0; j < 8; ++j) q[j] = tb[idx[j] * 4 + l];
                acc4(a0, q[0]); acc4(a1, q[1]); acc4(a2, q[2]); acc4(a3, q[3]);
                acc4(a0, q[4]); acc4(a1, q[5]); acc4(a2, q[6]); acc4(a3, q[7]);
                #pragma unroll
                for (int j = 0; j < 8; ++j) idx[j] = nx[j];
            }
            {
                uint2 q[8];
                #pragma unroll
                for (int j = 0; j < 8; ++j) q[j] = tb[idx[j] * 4 + l];
                acc4(a0, q[0]); acc4(a1, q[1]); acc4(a2, q[2]); acc4(a3, q[3]);
                acc4(a0, q[4]); acc4(a1, q[5]); acc4(a2, q[6]); acc4(a3, q[7]);
                i += 8;
            }
        }
        for (; i < num; ++i) acc4(a0, tb[cp[i] * 4 + l]);
        float dv = dis[v];
        g = batch[v];
        r.x = ((a0.x + a1.x) + (a2.x + a3.x)) * dv;
        r.y = ((a0.y + a1.y) + (a2.y + a3.y)) * dv;
        r.z = ((a0.z + a1.z) + (a2.z + a3.z)) * dv;
        r.w = ((a0.w + a1.w) + (a2.w + a3.w)) * dv;
    }

    int g0 = __shfl(g, 0, 64);
    bool uni = __all(!valid || g == g0);
    if (uni) {
        float vv[4] = {r.x, r.y, r.z, r.w};
        #pragma unroll
        for (int j = 0; j < 4; ++j) {
            float val = vv[j];
            val += __shfl_xor(val, 4, 64);
            val += __shfl_xor(val, 8, 64);
            val += __shfl_xor(val, 16, 64);
            val += __shfl_xor(val, 32, 64);
            if (lane < 4) atomicAdd(&psum[g0 * C2 + lane * 4 + j], val);
        }
        unsigned long long mb = __ballot(valid && (l == 0));
        if (lane == 0 && mb) atomicAdd(&cs[g0], (float)__popcll(mb));
    } else {
        if (valid) {
            atomicAdd(&psum[g * C2 + l * 4 + 0], r.x);
            atomicAdd(&psum[g * C2 + l * 4 + 1], r.y);
            atomicAdd(&psum[g * C2 + l * 4 + 2], r.z);
            atomicAdd(&psum[g * C2 + l * 4 + 3], r.w);
            if (l == 0) atomicAdd(&cs[g], 1.0f);
        }
    }
    __syncthreads();
    for (int i = t; i < NG * C2; i += 256)
        if (psum[i] != 0.f) atomicAdd(&pool[i], psum[i]);
    if (t < NG && cs[t] != 0.f) atomicAdd(&cntf[t], cs[t]);

    // ---- fused final: last block reduces pool -> out -----------------------
    __threadfence();                                   // release pool/cntf
    if (t == 0) lastflag = (atomicAdd(donecnt, 1) == (int)gridDim.x - 1);
    __syncthreads();
    if (lastflag && t < NG) {
        float c = fmaxf(atomicAdd(&cntf[t], 0.0f), 1.0f);   // atomic read: coherent
        float inv = 1.0f / c;
        float s = lb[0];
        #pragma unroll
        for (int k = 0; k < C2; ++k) {
            s = fmaf(b2[k], lw[k], s);                      // bias fold
            s = fmaf(atomicAdd(&pool[t * C2 + k], 0.0f) * inv, lw[k], s);
        }
        out[t] = s;
    }
}

extern "C" void kernel_launch(void* const* d_in, const int* in_sizes, int n_in,
                              void* d_out, int out_size, void* d_ws, size_t ws_size,
                              hipStream_t stream) {
    const float* x     = (const float*)d_in[0];
    const int*   ei    = (const int*)d_in[1];
    const int*   batch = (const int*)d_in[2];
    const float* W1    = (const float*)d_in[3];
    const float* b1    = (const float*)d_in[4];
    const float* W2    = (const float*)d_in[5];
    const float* b2    = (const float*)d_in[6];
    const float* lw    = (const float*)d_in[7];
    const float* lb    = (const float*)d_in[8];
    float* out = (float*)d_out;

    float*    wsf = (float*)d_ws;
    int*      wsi = (int*)d_ws;
    unsigned* wsu = (unsigned*)d_ws;

    int*      bcnt     = wsi + OFF_BCNT;
    float*    pool     = wsf + OFF_POOL;
    float*    cntf     = wsf + OFF_CNTF;
    int*      donecnt  = wsi + OFF_DONE;
    int*      runstart = wsi + OFF_RUN;
    int*      rowstart = wsi + OFF_ROW;
    float*    dis      = wsf + OFF_DIS;
    unsigned* edgebuf  = wsu + OFF_EDG;
    unsigned* xs1      = wsu + OFF_XS1;    // aliases edgebuf (dead after fillfused)
    unsigned* xs2b     = wsu + OFF_XS2B;
    int*      colidx   = wsi + OFF_COL;

    const int* S = ei;            // edge_index[0] (src)
    const int* D = ei + NE;       // edge_index[1] (dst)

    hipMemsetAsync(wsi + OFF_BCNT, 0, 2304 * sizeof(int), stream);  // bcnt+pool+cntf+done

    k_part       <<<NW, 512, 0, stream>>>(S, D, edgebuf, runstart, bcnt);
    k_fillfused  <<<NBKT, 256, 0, stream>>>(edgebuf, runstart, bcnt, rowstart, dis, colidx);
    k_gemm1      <<<(NN + 127) / 128, 256, 0, stream>>>(x, W1, dis, xs1);
    k_gather1    <<<NN / 32, 256, 0, stream>>>(xs1, colidx, rowstart, dis, b1, W2, xs2b);
    k_gather2    <<<(NN + 63) / 64, 256, 0, stream>>>(xs2b, colidx, rowstart, dis, batch,
                                                      pool, cntf, donecnt, b2, lw, lb, out);
}

// Round 7
// 244.491 us; speedup vs baseline: 2.0331x; 1.4269x over previous
//
#include <hip/hip_runtime.h>

#define NN 100000
#define NE 3200000
#define NF 128
#define C1 32
#define C2 16
#define NG 64
#define BKT_SH 7
#define BKT_W  128
#define NBKT   782          // ceil(NN/128)
#define CH     8192         // edges per partition chunk
#define NW     391          // ceil(NE/CH)
#define RSTR   784          // runstart row stride (783 used)
#define MAPCAP 6400         // per-bucket flattened-edge capacity (mean 4092, sd 64)

// ---- workspace layout (4-byte element offsets) ----
// bcnt/pool/cntf adjacent -> ONE memset covers all zeroed state.
#define OFF_BCNT  0            // 1024 ints (782 used)
#define OFF_POOL  1024         // NG*C2 = 1024 floats
#define OFF_CNTF  2048         // NG floats (pad to 2304)
#define OFF_RUN   2304         // NW*RSTR = 306,544 ints -> 308,848
#define OFF_ROW   308848       // NN+1 ints -> 408,849 (pad to 408,864)
#define OFF_DIS   408864       // NN floats -> 508,864
#define OFF_EDG   508864       // NE uints (dead after fillfused); 16B aligned
// xs1 aliases edgebuf: ONLY legal because fillfused (last edgebuf reader) and
// gemm1 (xs1 writer) are SEPARATE kernels — do not fuse them (r5 fault).
#define OFF_XS1   OFF_EDG                  // NN*16 uints bf16x2 cols 0..31
#define OFF_XS2B  (OFF_EDG + NE)           // NN*8 uints bf16x2; 16B aligned
#define OFF_COL   (OFF_XS2B + NN*8)        // NE ints CSR col indices

// ---- bf16x2 pack/unpack (RNE) ----
__device__ __forceinline__ unsigned pack_bf2(float a, float b) {
    unsigned ua = __float_as_uint(a);
    unsigned ub = __float_as_uint(b);
    ua = (ua + 0x7fffu + ((ua >> 16) & 1u)) >> 16;
    ub = (ub + 0x7fffu + ((ub >> 16) & 1u)) & 0xffff0000u;
    return ua | ub;   // lo = a, hi = b
}
__device__ __forceinline__ float2 unpack_bf2(unsigned u) {
    return make_float2(__uint_as_float(u << 16), __uint_as_float(u & 0xffff0000u));
}
__device__ __forceinline__ void acc4(float4& a, uint2 q) {
    float2 f0 = unpack_bf2(q.x), f1 = unpack_bf2(q.y);
    a.x += f0.x; a.y += f0.y; a.z += f1.x; a.w += f1.y;
}

// ---------------- k_part: per-chunk counting sort by bucket -----------------
__global__ __launch_bounds__(512) void k_part(
    const int* __restrict__ S, const int* __restrict__ D,
    unsigned* __restrict__ edgebuf, int* __restrict__ runstart,
    int* __restrict__ bcnt)
{
    __shared__ int lhist[1024];
    __shared__ int lstart[1024];
    __shared__ int lcur[NBKT];
    __shared__ int wsum[8];
    __shared__ unsigned lsort[CH];
    const int w = blockIdx.x;
    const int t = threadIdx.x;
    const int e0 = w * CH;
    const int n = min(CH, NE - e0);     // 8192 or 5120 (last); both %4 == 0
    const int n4 = n >> 2;
    const int4* __restrict__ S4 = (const int4*)(S + e0);
    const int4* __restrict__ D4 = (const int4*)(D + e0);

    for (int i = t; i < 1024; i += 512) lhist[i] = 0;
    __syncthreads();
    for (int i = t; i < n4; i += 512) {
        int4 d = D4[i];
        atomicAdd(&lhist[(unsigned)d.x >> BKT_SH], 1);
        atomicAdd(&lhist[(unsigned)d.y >> BKT_SH], 1);
        atomicAdd(&lhist[(unsigned)d.z >> BKT_SH], 1);
        atomicAdd(&lhist[(unsigned)d.w >> BKT_SH], 1);
    }
    __syncthreads();
    for (int i = t; i < NBKT; i += 512) atomicAdd(&bcnt[i], lhist[i]);

    int c0 = lhist[t * 2 + 0], c1 = lhist[t * 2 + 1];
    int ts = c0 + c1;
    const int lane = t & 63, wv = t >> 6;
    int sc = ts;
    #pragma unroll
    for (int off = 1; off < 64; off <<= 1) {
        int v = __shfl_up(sc, off, 64);
        if (lane >= off) sc += v;
    }
    if (lane == 63) wsum[wv] = sc;
    __syncthreads();
    int wo = 0;
    #pragma unroll
    for (int i = 0; i < 8; ++i) wo += (i < wv) ? wsum[i] : 0;
    int excl = sc - ts + wo;
    lstart[t * 2 + 0] = excl;
    lstart[t * 2 + 1] = excl + c0;
    __syncthreads();

    for (int i = t; i < 783; i += 512) runstart[w * RSTR + i] = lstart[i];
    for (int i = t; i < NBKT; i += 512) lcur[i] = lstart[i];
    __syncthreads();
    for (int i = t; i < n4; i += 512) {
        int4 s = S4[i];
        int4 d = D4[i];
        { int p = atomicAdd(&lcur[(unsigned)d.x >> BKT_SH], 1);
          lsort[p] = ((unsigned)s.x << BKT_SH) | ((unsigned)d.x & (BKT_W - 1)); }
        { int p = atomicAdd(&lcur[(unsigned)d.y >> BKT_SH], 1);
          lsort[p] = ((unsigned)s.y << BKT_SH) | ((unsigned)d.y & (BKT_W - 1)); }
        { int p = atomicAdd(&lcur[(unsigned)d.z >> BKT_SH], 1);
          lsort[p] = ((unsigned)s.z << BKT_SH) | ((unsigned)d.z & (BKT_W - 1)); }
        { int p = atomicAdd(&lcur[(unsigned)d.w >> BKT_SH], 1);
          lsort[p] = ((unsigned)s.w << BKT_SH) | ((unsigned)d.w & (BKT_W - 1)); }
    }
    __syncthreads();
    {
        uint4* __restrict__ eb4 = (uint4*)(edgebuf + e0);
        const uint4* __restrict__ ls4 = (const uint4*)lsort;
        for (int i = t; i < n4; i += 512) eb4[i] = ls4[i];
    }
}

// ---------------- fused per-bucket fill (bscan folded, LDS edge staging) ----
__global__ __launch_bounds__(256) void k_fillfused(
    const unsigned* __restrict__ edgebuf, const int* __restrict__ runstart,
    const int* __restrict__ bcnt,
    int* __restrict__ rowstart, float* __restrict__ dis, int* __restrict__ colidx)
{
    __shared__ int rl[NW];
    __shared__ int pfx[NW];
    __shared__ int basea[NW];
    __shared__ unsigned short map[MAPCAP];
    __shared__ unsigned ebuf[MAPCAP];     // staged edges: global read ONCE
    __shared__ int lcnt[BKT_W];
    __shared__ int lcur[BKT_W];
    __shared__ int wsum[4];
    __shared__ int hs1;
    const int b = blockIdx.x;
    const int t = threadIdx.x;
    const int lane = t & 63, wv = t >> 6;

    // --- bs = sum(bcnt[0..b)) : strided + full-wave xor reduce
    int accp = 0;
    for (int i = t; i < b; i += 256) accp += bcnt[i];
    #pragma unroll
    for (int off = 1; off < 64; off <<= 1) accp += __shfl_xor(accp, off, 64);
    if (lane == 0) wsum[wv] = accp;

    for (int w = t; w < NW; w += 256) {
        int s0 = runstart[w * RSTR + b];
        int s1 = runstart[w * RSTR + b + 1];
        basea[w] = s0;
        rl[w] = s1 - s0;
    }
    if (t < BKT_W) lcnt[t] = 0;
    __syncthreads();
    const int bs = wsum[0] + wsum[1] + wsum[2] + wsum[3];

    // --- scan rl (391 entries, 2/thread, wave-shuffle)
    int w0 = t * 2;
    int c0 = (w0 < NW) ? rl[w0] : 0;
    int c1 = (w0 + 1 < NW) ? rl[w0 + 1] : 0;
    int ts = c0 + c1;
    int sc = ts;
    #pragma unroll
    for (int off = 1; off < 64; off <<= 1) {
        int v = __shfl_up(sc, off, 64);
        if (lane >= off) sc += v;
    }
    __syncthreads();                       // all bs-reads done before wsum reuse
    if (lane == 63) wsum[wv] = sc;
    __syncthreads();
    int wo = 0;
    #pragma unroll
    for (int i = 0; i < 4; ++i) wo += (i < wv) ? wsum[i] : 0;
    const int total = wsum[0] + wsum[1] + wsum[2] + wsum[3];
    int excl0 = sc - ts + wo;
    if (w0 < NW)     pfx[w0]     = excl0;
    if (w0 + 1 < NW) pfx[w0 + 1] = excl0 + c0;
    __syncthreads();

    for (int w = t; w < NW; w += 256) {
        int p = pfx[w], len = rl[w];
        basea[w] = w * CH + basea[w] - p;
        for (int i = 0; i < len; ++i) map[p + i] = (unsigned short)w;
    }
    __syncthreads();
    // count pass: read each edge ONCE from global, stage in LDS
    for (int j = t; j < total; j += 256) {
        unsigned p = edgebuf[basea[map[j]] + j];
        ebuf[j] = p;
        atomicAdd(&lcnt[p & (BKT_W - 1)], 1);
    }
    __syncthreads();

    // --- 128-wide scan of lcnt: 2-wave shuffle scan, 1 barrier
    int myc = 0, sc2 = 0;
    if (t < BKT_W) {
        myc = lcnt[t];
        sc2 = myc;
        #pragma unroll
        for (int off = 1; off < 64; off <<= 1) {
            int v = __shfl_up(sc2, off, 64);
            if (lane >= off) sc2 += v;
        }
        if (t == 63) hs1 = sc2;
    }
    __syncthreads();
    if (t < BKT_W) {
        int excl = sc2 - myc + ((t >= 64) ? hs1 : 0);
        int node = b * BKT_W + t;
        if (node < NN) {
            rowstart[node] = bs + excl;
            dis[node] = rsqrtf((float)myc + 1.0f);
        }
        lcur[t] = bs + excl;
    }
    if (b == 0 && t == 0) rowstart[NN] = NE;
    __syncthreads();
    // scatter pass from LDS-staged edges (no second global edgebuf read)
    for (int j = t; j < total; j += 256) {
        unsigned p = ebuf[j];
        int pos = atomicAdd(&lcur[p & (BKT_W - 1)], 1);
        colidx[pos] = (int)(p >> BKT_SH);
    }
}

// ---------------- GEMM1: xs1 = bf16x2{(x @ W1) * dis}, 64B/node row ---------
__global__ __launch_bounds__(256) void k_gemm1(
    const float* __restrict__ x, const float* __restrict__ W1,
    const float* __restrict__ dis,
    unsigned* __restrict__ xs1)
{
    __shared__ float xls[128 * 33];
    __shared__ float wls[32 * 32];
    const int t = threadIdx.x;
    const int tc = t & 7;
    const int tr = t >> 3;
    const int base = blockIdx.x * 128;

    float a[4][4] = {};

    for (int k0 = 0; k0 < NF; k0 += 32) {
        {
            int i = t * 4;
            int kk = i >> 5, c = i & 31;
            *(float4*)&wls[kk * 32 + c] = *(const float4*)&W1[(k0 + kk) * C1 + c];
        }
        #pragma unroll
        for (int r = 0; r < 4; ++r) {
            int n = (t >> 3) + r * 32;
            int j = (t & 7) * 4;
            int node = base + n;
            float4 v = make_float4(0.f, 0.f, 0.f, 0.f);
            if (node < NN) v = *(const float4*)&x[(long long)node * NF + k0 + j];
            xls[n * 33 + j + 0] = v.x;
            xls[n * 33 + j + 1] = v.y;
            xls[n * 33 + j + 2] = v.z;
            xls[n * 33 + j + 3] = v.w;
        }
        __syncthreads();
        #pragma unroll 8
        for (int kk = 0; kk < 32; ++kk) {
            float4 w = *(const float4*)&wls[kk * 32 + tc * 4];
            #pragma unroll
            for (int i = 0; i < 4; ++i) {
                float xv = xls[(tr * 4 + i) * 33 + kk];
                a[i][0] = fmaf(xv, w.x, a[i][0]);
                a[i][1] = fmaf(xv, w.y, a[i][1]);
                a[i][2] = fmaf(xv, w.z, a[i][2]);
                a[i][3] = fmaf(xv, w.w, a[i][3]);
            }
        }
        __syncthreads();
    }
    #pragma unroll
    for (int i = 0; i < 4; ++i) {
        int node = base + tr * 4 + i;
        if (node < NN) {
            float dv = dis[node];
            uint2 o;
            o.x = pack_bf2(a[i][0] * dv, a[i][1] * dv);
            o.y = pack_bf2(a[i][2] * dv, a[i][3] * dv);
            *(uint2*)&xs1[node * 16 + tc * 2] = o;
        }
    }
}

// ---------------- gather layer1 + fused GEMM2 epilogue (r3, unchanged) ------
__global__ __launch_bounds__(256) void k_gather1(
    const unsigned* __restrict__ xs1, const int* __restrict__ colidx,
    const int* __restrict__ rowstart, const float* __restrict__ dis,
    const float* __restrict__ b1, const float* __restrict__ W2,
    unsigned* __restrict__ xs2b)
{
    __shared__ float w2s[C1 * C2];
    __shared__ float hrow[32 * 33];
    const int t = threadIdx.x;
    if (t < 128) *(float4*)&w2s[t * 4] = *(const float4*)&W2[t * 4];
    const int l = t & 7;
    const int n = t >> 3;
    const int v = blockIdx.x * 32 + n;   // NN = 100000 = 3125*32 exactly

    const int start = rowstart[v];
    const int num = rowstart[v + 1] - start;
    const int* __restrict__ cp = &colidx[start];
    const uint2* __restrict__ tb = (const uint2*)xs1;   // row v = tb[v*8 + l]
    float4 a0 = make_float4(0.f, 0.f, 0.f, 0.f);
    float4 a1 = a0, a2 = a0, a3 = a0;
    acc4(a0, tb[v * 8 + l]);                            // self loop
    int i = 0;
    if (num >= 8) {
        int idx[8];
        #pragma unroll
        for (int j = 0; j < 8; ++j) idx[j] = cp[j];
        for (; i + 16 <= num; i += 8) {
            int nx[8];
            #pragma unroll
            for (int j = 0; j < 8; ++j) nx[j] = cp[i + 8 + j];
            uint2 q[8];
            #pragma unroll
            for (int j = 0; j < 8; ++j) q[j] = tb[idx[j] * 8 + l];
            acc4(a0, q[0]); acc4(a1, q[1]); acc4(a2, q[2]); acc4(a3, q[3]);
            acc4(a0, q[4]); acc4(a1, q[5]); acc4(a2, q[6]); acc4(a3, q[7]);
            #pragma unroll
            for (int j = 0; j < 8; ++j) idx[j] = nx[j];
        }
        {   // drain the pipelined 8
            uint2 q[8];
            #pragma unroll
            for (int j = 0; j < 8; ++j) q[j] = tb[idx[j] * 8 + l];
            acc4(a0, q[0]); acc4(a1, q[1]); acc4(a2, q[2]); acc4(a3, q[3]);
            acc4(a0, q[4]); acc4(a1, q[5]); acc4(a2, q[6]); acc4(a3, q[7]);
            i += 8;
        }
    }
    for (; i < num; ++i) acc4(a0, tb[cp[i] * 8 + l]);
    float ax = (a0.x + a1.x) + (a2.x + a3.x);
    float ay = (a0.y + a1.y) + (a2.y + a3.y);
    float az = (a0.z + a1.z) + (a2.z + a3.z);
    float aw = (a0.w + a1.w) + (a2.w + a3.w);
    const float dv = dis[v];

    hrow[n * 33 + l * 4 + 0] = fmaxf(fmaf(ax, dv, b1[l * 4 + 0]), 0.f);
    hrow[n * 33 + l * 4 + 1] = fmaxf(fmaf(ay, dv, b1[l * 4 + 1]), 0.f);
    hrow[n * 33 + l * 4 + 2] = fmaxf(fmaf(az, dv, b1[l * 4 + 2]), 0.f);
    hrow[n * 33 + l * 4 + 3] = fmaxf(fmaf(aw, dv, b1[l * 4 + 3]), 0.f);
    __syncthreads();

    // GEMM2 epilogue: lane l computes output cols 2l, 2l+1
    const float* hr = &hrow[n * 33];
    float s0 = 0.f, s1 = 0.f;
    #pragma unroll
    for (int k = 0; k < 32; ++k) {
        float hv = hr[k];
        s0 = fmaf(hv, w2s[k * C2 + 2 * l + 0], s0);
        s1 = fmaf(hv, w2s[k * C2 + 2 * l + 1], s1);
    }
    xs2b[v * 8 + l] = pack_bf2(s0 * dv, s1 * dv);
}

// ---------------- gather layer2 + fused mean-pool (r3, unchanged) -----------
__global__ __launch_bounds__(256) void k_gather2(
    const unsigned* __restrict__ xs2b, const int* __restrict__ colidx,
    const int* __restrict__ rowstart, const float* __restrict__ dis,
    const int* __restrict__ batch,
    float* __restrict__ pool, float* __restrict__ cntf)
{
    __shared__ float psum[NG * C2];
    __shared__ float cs[NG];
    const int t = threadIdx.x;
    for (int i = t; i < NG * C2; i += 256) psum[i] = 0.f;
    if (t < NG) cs[t] = 0.f;
    __syncthreads();

    const int l = t & 3;
    const int n = t >> 2;                 // 0..63
    const int v = blockIdx.x * 64 + n;
    const bool valid = v < NN;
    const int lane = t & 63;

    float4 r = make_float4(0.f, 0.f, 0.f, 0.f);
    int g = 0;
    if (valid) {
        const int start = rowstart[v];
        const int num = rowstart[v + 1] - start;
        const int* __restrict__ cp = &colidx[start];
        const uint2* __restrict__ tb = (const uint2*)xs2b;  // row v = tb[v*4 + l]
        float4 a0 = make_float4(0.f, 0.f, 0.f, 0.f);
        float4 a1 = a0, a2 = a0, a3 = a0;
        acc4(a0, tb[v * 4 + l]);                            // self loop
        int i = 0;
        if (num >= 8) {
            int idx[8];
            #pragma unroll
            for (int j = 0; j < 8; ++j) idx[j] = cp[j];
            for (; i + 16 <= num; i += 8) {
                int nx[8];
                #pragma unroll
                for (int j = 0; j < 8; ++j) nx[j] = cp[i + 8 + j];
                uint2 q[8];
                #pragma unroll
                for (int j = 0; j < 8; ++j) q[j] = tb[idx[j] * 4 + l];
                acc4(a0, q[0]); acc4(a1, q[1]); acc4(a2, q[2]); acc4(a3, q[3]);
                acc4(a0, q[4]); acc4(a1, q[5]); acc4(a2, q[6]); acc4(a3, q[7]);
                #pragma unroll
                for (int j = 0; j < 8; ++j) idx[j] = nx[j];
            }
            {
                uint2 q[8];
                #pragma unroll
                for (int j = 0; j < 8; ++j) q[j] = tb[idx[j] * 4 + l];
                acc4(a0, q[0]); acc4(a1, q[1]); acc4(a2, q[2]); acc4(a3, q[3]);
                acc4(a0, q[4]); acc4(a1, q[5]); acc4(a2, q[6]); acc4(a3, q[7]);
                i += 8;
            }
        }
        for (; i < num; ++i) acc4(a0, tb[cp[i] * 4 + l]);
        float dv = dis[v];
        g = batch[v];
        r.x = ((a0.x + a1.x) + (a2.x + a3.x)) * dv;
        r.y = ((a0.y + a1.y) + (a2.y + a3.y)) * dv;
        r.z = ((a0.z + a1.z) + (a2.z + a3.z)) * dv;
        r.w = ((a0.w + a1.w) + (a2.w + a3.w)) * dv;
    }

    int g0 = __shfl(g, 0, 64);
    bool uni = __all(!valid || g == g0);
    if (uni) {
        float vv[4] = {r.x, r.y, r.z, r.w};
        #pragma unroll
        for (int j = 0; j < 4; ++j) {
            float val = vv[j];
            val += __shfl_xor(val, 4, 64);
            val += __shfl_xor(val, 8, 64);
            val += __shfl_xor(val, 16, 64);
            val += __shfl_xor(val, 32, 64);
            if (lane < 4) atomicAdd(&psum[g0 * C2 + lane * 4 + j], val);
        }
        unsigned long long mb = __ballot(valid && (l == 0));
        if (lane == 0 && mb) atomicAdd(&cs[g0], (float)__popcll(mb));
    } else {
        if (valid) {
            atomicAdd(&psum[g * C2 + l * 4 + 0], r.x);
            atomicAdd(&psum[g * C2 + l * 4 + 1], r.y);
            atomicAdd(&psum[g * C2 + l * 4 + 2], r.z);
            atomicAdd(&psum[g * C2 + l * 4 + 3], r.w);
            if (l == 0) atomicAdd(&cs[g], 1.0f);
        }
    }
    __syncthreads();
    for (int i = t; i < NG * C2; i += 256)
        if (psum[i] != 0.f) atomicAdd(&pool[i], psum[i]);
    if (t < NG && cs[t] != 0.f) atomicAdd(&cntf[t], cs[t]);
}

// ---------------- final: out[g] = (pool/cnt + b2) @ lw + lb -----------------
__global__ void k_final(const float* __restrict__ pool, const float* __restrict__ cntf,
                        const float* __restrict__ b2,
                        const float* __restrict__ lw, const float* __restrict__ lb,
                        float* __restrict__ out)
{
    int g = threadIdx.x;
    if (g < NG) {
        float c = fmaxf(cntf[g], 1.0f);
        float inv = 1.0f / c;
        float s = lb[0];
        #pragma unroll
        for (int k = 0; k < C2; ++k) {
            s = fmaf(b2[k], lw[k], s);                    // bias fold
            s = fmaf(pool[g * C2 + k] * inv, lw[k], s);
        }
        out[g] = s;
    }
}

extern "C" void kernel_launch(void* const* d_in, const int* in_sizes, int n_in,
                              void* d_out, int out_size, void* d_ws, size_t ws_size,
                              hipStream_t stream) {
    const float* x     = (const float*)d_in[0];
    const int*   ei    = (const int*)d_in[1];
    const int*   batch = (const int*)d_in[2];
    const float* W1    = (const float*)d_in[3];
    const float* b1    = (const float*)d_in[4];
    const float* W2    = (const float*)d_in[5];
    const float* b2    = (const float*)d_in[6];
    const float* lw    = (const float*)d_in[7];
    const float* lb    = (const float*)d_in[8];
    float* out = (float*)d_out;

    float*    wsf = (float*)d_ws;
    int*      wsi = (int*)d_ws;
    unsigned* wsu = (unsigned*)d_ws;

    int*      bcnt     = wsi + OFF_BCNT;
    float*    pool     = wsf + OFF_POOL;
    float*    cntf     = wsf + OFF_CNTF;
    int*      runstart = wsi + OFF_RUN;
    int*      rowstart = wsi + OFF_ROW;
    float*    dis      = wsf + OFF_DIS;
    unsigned* edgebuf  = wsu + OFF_EDG;
    unsigned* xs1      = wsu + OFF_XS1;    // aliases edgebuf (dead after fillfused)
    unsigned* xs2b     = wsu + OFF_XS2B;
    int*      colidx   = wsi + OFF_COL;

    const int* S = ei;            // edge_index[0] (src)
    const int* D = ei + NE;       // edge_index[1] (dst)

    hipMemsetAsync(wsi + OFF_BCNT, 0, 2304 * sizeof(int), stream);  // bcnt+pool+cntf

    k_part       <<<NW, 512, 0, stream>>>(S, D, edgebuf, runstart, bcnt);
    k_fillfused  <<<NBKT, 256, 0, stream>>>(edgebuf, runstart, bcnt, rowstart, dis, colidx);
    k_gemm1      <<<(NN + 127) / 128, 256, 0, stream>>>(x, W1, dis, xs1);
    k_gather1    <<<NN / 32, 256, 0, stream>>>(xs1, colidx, rowstart, dis, b1, W2, xs2b);
    k_gather2    <<<(NN + 63) / 64, 256, 0, stream>>>(xs2b, colidx, rowstart, dis, batch, pool, cntf);
    k_final      <<<1, 64, 0, stream>>>(pool, cntf, b2, lw, lb, out);
}